// Round 13
// baseline (207.403 us; speedup 1.0000x reference)
//
#include <hip/hip_runtime.h>

// CenterShift: out[n,o] = x[n] * (celu(celu((pos_j-pos_i)@w11+b11)@w12+b12) @ w13 + b13)[o]
// N = 2097152, dims 3 -> 16 -> 64 -> 64, fp32 in/out.
//
// Round 13 = r12 with ONE change: persistent b3v registers removed; layer-3
// bias is reloaded as float4 per (t2,u) from b13 (L1-broadcast, r6-proven).
// Rationale: r11/r12 cut LDS to 32KB but stayed ~3 waves/SIMD because the
// VGPR bucket (not LDS) was binding (~130-140 regs). Dropping 16 persistent
// regs targets the <=128 bucket so LDS(32KB) and VGPR align at 4 blocks/CU
// = 16 waves/CU (+33% TLP vs r9's 12).
//  - scalar layer-2 final (MFMA-l2 lost 4x); contiguous 1KB-per-instr stores
//    (r9's +24% win); in-place f16 bounce into dead h2 rows (r12); 4-tile
//    loop + pos prefetch; per-wave LDS, no __syncthreads.

typedef __attribute__((ext_vector_type(8))) _Float16 f16x8;
typedef __attribute__((ext_vector_type(4))) float f32x4;

#define TILES 4

__device__ __forceinline__ float celu1(float a) {
    return a > 0.0f ? a : __expf(a) - 1.0f;
}

__global__ __launch_bounds__(256) void centershift_kernel(
    const float* __restrict__ x,
    const float* __restrict__ pos_i,
    const float* __restrict__ pos_j,
    const float* __restrict__ w11, const float* __restrict__ b11,
    const float* __restrict__ w12, const float* __restrict__ b12,
    const float* __restrict__ w13, const float* __restrict__ b13,
    float* __restrict__ out, int n)
{
    // 8 KB per wave: h2 tile, with per-group in-place f16 bounce during layer 3
    __shared__ __align__(16) _Float16 h2s[4][4096];   // 32 KB/block

    const int lane = threadIdx.x & 63;
    const int wid  = threadIdx.x >> 6;
    const int g    = lane >> 4;    // 16-lane group 0..3
    const int r16  = lane & 15;
    const int swzR = (r16 & 7) << 4;

    const int wbase = (blockIdx.x * 4 + wid) * (64 * TILES);
    if (wbase >= n) return;

    char* h2b = (char*)&h2s[wid][0];

    // ---- hoisted fragments (issue first; overlap tile-0 compute) ----
    // layer-3 A = w13^T: A[row = u*16 + r16][k = kh*32 + g*8 + j]
    f16x8 a3[4][2];
#pragma unroll
    for (int u = 0; u < 4; ++u)
#pragma unroll
        for (int kh = 0; kh < 2; ++kh) {
            f16x8 v;
#pragma unroll
            for (int j = 0; j < 8; ++j)
                v[j] = (_Float16)w13[(kh * 32 + g * 8 + j) * 64 + u * 16 + r16];
            a3[u][kh] = v;
        }
    // NOTE: no persistent b3v -- bias reloaded per use in the epilogue.

    // ---- preload tile-0 pos (lane = its own point) ----
    const float* pip = pos_i + 3 * (size_t)(wbase + lane);
    const float* pjp = pos_j + 3 * (size_t)(wbase + lane);
    float3 cpi = *reinterpret_cast<const float3*>(pip);
    float3 cpj = *reinterpret_cast<const float3*>(pjp);

    const int swzW = (lane & 7) << 4;
    const int rowW = lane * 128;

#pragma unroll 1
    for (int t = 0; t < TILES; ++t) {
        const int tb = wbase + t * 64;
        if (tb >= n) break;

        const float p0 = cpj.x - cpi.x, p1 = cpj.y - cpi.y, p2 = cpj.z - cpi.z;

        // ---- layer 1: 3 -> 16 ----
        float h1[16];
#pragma unroll
        for (int j = 0; j < 16; ++j) {
            float a = b11[j];
            a = fmaf(p0, w11[j], a);
            a = fmaf(p1, w11[16 + j], a);
            a = fmaf(p2, w11[32 + j], a);
            h1[j] = celu1(a);
        }

        // prefetch next tile's pos (hidden under the compute below)
        if (t + 1 < TILES) {
            cpi = *reinterpret_cast<const float3*>(pip + (t + 1) * 192);
            cpj = *reinterpret_cast<const float3*>(pjp + (t + 1) * 192);
        }

        // ---- layer 2: 16 -> 64 scalar (wave-uniform weights -> s_load),
        //      streamed to swizzled h2 LDS in f16x8 chunks ----
        for (int c = 0; c < 8; ++c) {
            f16x8 v;
#pragma unroll
            for (int j = 0; j < 8; ++j) {
                const int o = c * 8 + j;
                float a = b12[o];
#pragma unroll
                for (int k = 0; k < 16; ++k)
                    a = fmaf(h1[k], w12[k * 64 + o], a);
                v[j] = (_Float16)celu1(a);
            }
            *reinterpret_cast<f16x8*>(h2b + (rowW + ((c * 16) ^ swzW))) = v;
        }

        // ---- layer 3: per 16-point group: bb reads -> MFMA -> in-place f16
        //      bounce into the group's own (now dead) h2 rows -> drain as
        //      contiguous 1KB-per-instruction stores ----
#pragma unroll
        for (int t2 = 0; t2 < 4; ++t2) {
            const int pt    = t2 * 16 + r16;
            const int rowR  = pt * 128;
            const int gbase = t2 * 2048;           // group's 16 rows (2 KB)
            const f16x8 bb0 = *reinterpret_cast<const f16x8*>(h2b + (rowR + ((     g * 16) ^ swzR)));
            const f16x8 bb1 = *reinterpret_cast<const f16x8*>(h2b + (rowR + ((64 + g * 16) ^ swzR)));
            const float xvt = x[tb + pt];          // 1 line, L1 broadcast
#pragma unroll
            for (int u = 0; u < 4; ++u) {
                // bias for o = u*16 + g*4 + {0..3}: 16B load, L1-broadcast
                const float4 bv = *reinterpret_cast<const float4*>(b13 + u * 16 + g * 4);
                f32x4 acc = { bv.x, bv.y, bv.z, bv.w };
                acc = __builtin_amdgcn_mfma_f32_16x16x32_f16(a3[u][0], bb0, acc, 0, 0, 0);
                acc = __builtin_amdgcn_mfma_f32_16x16x32_f16(a3[u][1], bb1, acc, 0, 0, 0);
                // pack final f32 -> f16 (adds ~0.002-0.015 abs err; budget OK)
                union { _Float16 h[4]; unsigned long long v; } pk;
                pk.h[0] = (_Float16)(acc[0] * xvt);
                pk.h[1] = (_Float16)(acc[1] * xvt);
                pk.h[2] = (_Float16)(acc[2] * xvt);
                pk.h[3] = (_Float16)(acc[3] * xvt);
                // bounce byte (within group): row r16, off = u*32+g*8,
                // XOR-swizzled by (r16&15)<<3 (bijective, min-phase b64)
                const int wb = gbase + r16 * 128 + ((u * 32 + g * 8) ^ ((r16 & 15) << 3));
                *reinterpret_cast<unsigned long long*>(h2b + wb) = pk.v;
            }
            // drain: 4 instructions, each one contiguous 1KB chunk (fill pattern)
            float* og = out + (size_t)(tb + t2 * 16) * 64;
#pragma unroll
            for (int k = 0; k < 4; ++k) {
                const int ptl = k * 4 + (lane >> 4);   // local point 0..15
                const int rb  = gbase + ptl * 128 + (((lane & 15) * 8) ^ ((ptl & 15) << 3));
                union { _Float16 h[4]; unsigned long long v; } pk;
                pk.v = *reinterpret_cast<const unsigned long long*>(h2b + rb);
                float4 v4 = { (float)pk.h[0], (float)pk.h[1], (float)pk.h[2], (float)pk.h[3] };
                *reinterpret_cast<float4*>(og + k * 256 + lane * 4) = v4;
            }
        }
    }
}

extern "C" void kernel_launch(void* const* d_in, const int* in_sizes, int n_in,
                              void* d_out, int out_size, void* d_ws, size_t ws_size,
                              hipStream_t stream) {
    const float* x     = (const float*)d_in[0];
    const float* pos_i = (const float*)d_in[1];
    const float* pos_j = (const float*)d_in[2];
    const float* w11   = (const float*)d_in[3];
    const float* b11   = (const float*)d_in[4];
    const float* w12   = (const float*)d_in[5];
    const float* b12   = (const float*)d_in[6];
    const float* w13   = (const float*)d_in[7];
    const float* b13   = (const float*)d_in[8];
    float* out = (float*)d_out;

    const int n = in_sizes[0];                        // N (x is [N,1])
    const int per_block = 256 * TILES;                // 4 waves x 4 tiles x 64 pts
    const int blocks = (n + per_block - 1) / per_block;
    centershift_kernel<<<blocks, 256, 0, stream>>>(
        x, pos_i, pos_j, w11, b11, w12, b12, w13, b13, out, n);
}

// Round 15
// 124.188 us; speedup vs baseline: 1.6701x; 1.6701x over previous
//
#include <hip/hip_runtime.h>

// CenterShift: out[n,o] = x[n] * (celu(celu((pos_j-pos_i)@w11+b11)@w12+b12) @ w13 + b13)[o]
// N = 2097152, dims 3 -> 16 -> 64 -> 64, fp32 in/out.
//
// Round 15 = r14 with the compile fix: __builtin_nontemporal_store requires
// an ext_vector pointer, not HIP_vector_type float4 -> use f32x4 throughout
// the drain. Otherwise byte-identical to r9 (146us best) + nt stores.
// Theory unchanged: 512MB output stream write-allocates through the 4MiB/XCD
// L2; nt streams past it, removing eviction backpressure.
//  - scalar layer-2 (final); r9's 48KB LDS; contiguous 1KB-per-instr stores
//    via f32 LDS bounce; 4-tile wave loop + pos prefetch; no __syncthreads

typedef __attribute__((ext_vector_type(8))) _Float16 f16x8;
typedef __attribute__((ext_vector_type(4))) float f32x4;

#define TILES 4

__device__ __forceinline__ float celu1(float a) {
    return a > 0.0f ? a : __expf(a) - 1.0f;
}

__global__ __launch_bounds__(256) void centershift_kernel(
    const float* __restrict__ x,
    const float* __restrict__ pos_i,
    const float* __restrict__ pos_j,
    const float* __restrict__ w11, const float* __restrict__ b11,
    const float* __restrict__ w12, const float* __restrict__ b12,
    const float* __restrict__ w13, const float* __restrict__ b13,
    float* __restrict__ out, int n)
{
    __shared__ __align__(16) _Float16 h2s[4][64 * 64];  // 8 KB/wave, swizzled
    __shared__ __align__(16) float    stg[4][1024];     // 4 KB/wave bounce

    const int lane = threadIdx.x & 63;
    const int wid  = threadIdx.x >> 6;
    const int g    = lane >> 4;    // 16-lane group 0..3
    const int r16  = lane & 15;

    const int wbase = (blockIdx.x * 4 + wid) * (64 * TILES);
    if (wbase >= n) return;

    char* h2b  = (char*)&h2s[wid][0];
    char* stgb = (char*)&stg[wid][0];

    // ---- hoisted fragments (issue first; overlap tile-0 compute) ----
    // layer-3 A = w13^T: A[row = u*16 + r16][k = kh*32 + g*8 + j]
    f16x8 a3[4][2];
#pragma unroll
    for (int u = 0; u < 4; ++u)
#pragma unroll
        for (int kh = 0; kh < 2; ++kh) {
            f16x8 v;
#pragma unroll
            for (int j = 0; j < 8; ++j)
                v[j] = (_Float16)w13[(kh * 32 + g * 8 + j) * 64 + u * 16 + r16];
            a3[u][kh] = v;
        }
    // bias in C/D layout: lane holds o = u*16 + g*4 + rr
    float b3v[4][4];
#pragma unroll
    for (int u = 0; u < 4; ++u) {
        const float4 bv = *reinterpret_cast<const float4*>(b13 + u * 16 + g * 4);
        b3v[u][0] = bv.x; b3v[u][1] = bv.y; b3v[u][2] = bv.z; b3v[u][3] = bv.w;
    }

    // ---- preload tile-0 pos (lane = its own point) ----
    const float* pip = pos_i + 3 * (size_t)(wbase + lane);
    const float* pjp = pos_j + 3 * (size_t)(wbase + lane);
    float3 cpi = *reinterpret_cast<const float3*>(pip);
    float3 cpj = *reinterpret_cast<const float3*>(pjp);

    const int swzW = (lane & 7) << 4;
    const int rowW = lane * 128;
    const int swzR = (r16 & 7) << 4;

#pragma unroll 1
    for (int t = 0; t < TILES; ++t) {
        const int tb = wbase + t * 64;
        if (tb >= n) break;

        const float p0 = cpj.x - cpi.x, p1 = cpj.y - cpi.y, p2 = cpj.z - cpi.z;

        // ---- layer 1: 3 -> 16 ----
        float h1[16];
#pragma unroll
        for (int j = 0; j < 16; ++j) {
            float a = b11[j];
            a = fmaf(p0, w11[j], a);
            a = fmaf(p1, w11[16 + j], a);
            a = fmaf(p2, w11[32 + j], a);
            h1[j] = celu1(a);
        }

        // prefetch next tile's pos (hidden under the compute below)
        if (t + 1 < TILES) {
            cpi = *reinterpret_cast<const float3*>(pip + (t + 1) * 192);
            cpj = *reinterpret_cast<const float3*>(pjp + (t + 1) * 192);
        }

        // ---- layer 2: 16 -> 64 scalar (wave-uniform weights), to swizzled LDS ----
        for (int c = 0; c < 8; ++c) {
            f16x8 v;
#pragma unroll
            for (int j = 0; j < 8; ++j) {
                const int o = c * 8 + j;
                float a = b12[o];
#pragma unroll
                for (int k = 0; k < 16; ++k)
                    a = fmaf(h1[k], w12[k * 64 + o], a);
                v[j] = (_Float16)celu1(a);
            }
            *reinterpret_cast<f16x8*>(h2b + (rowW + ((c * 16) ^ swzW))) = v;
        }

        // ---- layer 3: MFMA -> LDS bounce -> contiguous 1KB-per-instr nt stores ----
#pragma unroll
        for (int t2 = 0; t2 < 4; ++t2) {
            const int pt   = t2 * 16 + r16;
            const int rowR = pt * 128;
            const f16x8 bb0 = *reinterpret_cast<const f16x8*>(h2b + (rowR + ((     g * 16) ^ swzR)));
            const f16x8 bb1 = *reinterpret_cast<const f16x8*>(h2b + (rowR + ((64 + g * 16) ^ swzR)));
            const float xvt = x[tb + pt];          // 1 line, L1 broadcast
#pragma unroll
            for (int u = 0; u < 4; ++u) {
                f32x4 acc = { b3v[u][0], b3v[u][1], b3v[u][2], b3v[u][3] };
                acc = __builtin_amdgcn_mfma_f32_16x16x32_f16(a3[u][0], bb0, acc, 0, 0, 0);
                acc = __builtin_amdgcn_mfma_f32_16x16x32_f16(a3[u][1], bb1, acc, 0, 0, 0);
                // lane holds ch c = u*4+g (16B block) of local point r16:
                // bounce byte = r16*256 + ((c*16) ^ ((r16&7)<<4))
                f32x4 o4 = { acc[0] * xvt, acc[1] * xvt, acc[2] * xvt, acc[3] * xvt };
                const int wb = r16 * 256 + (((u * 64 + g * 16)) ^ ((r16 & 7) << 4));
                *reinterpret_cast<f32x4*>(stgb + wb) = o4;
            }
            // drain: 4 instructions, each one contiguous 1KB chunk, non-temporal
            float* og = out + (size_t)(tb + t2 * 16) * 64;
#pragma unroll
            for (int k = 0; k < 4; ++k) {
                const int ptl = k * 4 + (lane >> 4);   // local point 0..15
                const int c   = lane & 15;             // 16B channel block
                const int rb  = ptl * 256 + ((c * 16) ^ ((ptl & 7) << 4));
                const f32x4 v = *reinterpret_cast<const f32x4*>(stgb + rb);
                __builtin_nontemporal_store(v, reinterpret_cast<f32x4*>(og + k * 256 + lane * 4));
            }
        }
    }
}

extern "C" void kernel_launch(void* const* d_in, const int* in_sizes, int n_in,
                              void* d_out, int out_size, void* d_ws, size_t ws_size,
                              hipStream_t stream) {
    const float* x     = (const float*)d_in[0];
    const float* pos_i = (const float*)d_in[1];
    const float* pos_j = (const float*)d_in[2];
    const float* w11   = (const float*)d_in[3];
    const float* b11   = (const float*)d_in[4];
    const float* w12   = (const float*)d_in[5];
    const float* b12   = (const float*)d_in[6];
    const float* w13   = (const float*)d_in[7];
    const float* b13   = (const float*)d_in[8];
    float* out = (float*)d_out;

    const int n = in_sizes[0];                        // N (x is [N,1])
    const int per_block = 256 * TILES;                // 4 waves x 4 tiles x 64 pts
    const int blocks = (n + per_block - 1) / per_block;
    centershift_kernel<<<blocks, 256, 0, stream>>>(
        x, pos_i, pos_j, w11, b11, w12, b12, w13, b13, out, n);
}